// Round 18
// baseline (376.035 us; speedup 1.0000x reference)
//
#include <hip/hip_runtime.h>
#include <stdint.h>

typedef unsigned short u16;
typedef __attribute__((ext_vector_type(4))) short s16x4;
typedef __attribute__((ext_vector_type(8))) short short8;
typedef __attribute__((ext_vector_type(4))) float f32x4;

// ---------- bf16 helpers (RNE) ----------
static __device__ __forceinline__ u16 f2bf(float f) {
    union { float f; uint32_t u; } c; c.f = f;
    uint32_t u = c.u;
    u += 0x7FFFu + ((u >> 16) & 1u);
    return (u16)(u >> 16);
}

// ---------- problem constants ----------
#define D_IN   2048
#define D_OUT  2048
#define MTOT   32768   // B*T
#define BK     64
#define NTM    32      // main K-tiles; tile 32 = LoRA tail

// async global->LDS, 16B/lane; LDS dest = wavebase + lane*16 (linear)
__device__ __forceinline__ void gload16(const u16* g, u16* l) {
    __builtin_amdgcn_global_load_lds(
        (const __attribute__((address_space(1))) void*)g,
        (__attribute__((address_space(3))) void*)l, 16, 0, 0);
}

// ---------- MERGED pre-pass: [0,1024) cast x + xa ; [1024,3072) W cast ; [3072,7168) Bp ----------
__global__ __launch_bounds__(256) void k_pre(
    const float* __restrict__ x, const float* __restrict__ W,
    const float* __restrict__ A, const float* __restrict__ Bm,
    const float* __restrict__ scal, const int* __restrict__ aidx,
    u16* __restrict__ xb, u16* __restrict__ Wb, u16* __restrict__ Bp,
    u16* __restrict__ xa)
{
    __shared__ __align__(16) u16 Xs[32 * BK];   // 4 KB
    __shared__ __align__(16) u16 Ps[64 * BK];   // 8 KB
    const int b = blockIdx.x, tid = threadIdx.x;

    if (b >= 1024) {
        if (b < 3072) {                   // W cast: 4M elems, 8/thread
            int i = ((b - 1024) * 256 + tid) * 8;
            const float4* p = (const float4*)(W + i);
            float4 v0 = p[0], v1 = p[1];
            short8 o;
            o[0]=f2bf(v0.x); o[1]=f2bf(v0.y); o[2]=f2bf(v0.z); o[3]=f2bf(v0.w);
            o[4]=f2bf(v1.x); o[5]=f2bf(v1.y); o[6]=f2bf(v1.z); o[7]=f2bf(v1.w);
            *(short8*)(Wb + i) = o;
        } else {                          // Bpad (a,n,64), cols 16..63 zero
            int i = (b - 3072) * 256 + tid;   // over 1048576
            int j = i & 63, n = (i >> 6) & 2047, a = i >> 17;
            Bp[i] = (j < 16) ? f2bf(Bm[((((a << 11) + n)) << 4) + j]) : (u16)0;
        }
        return;
    }

    // ---- cast + xa block: 32 rows of x ----
    const int lane = tid & 63, wid = tid >> 6;
    const int m0 = b << 5;
    const int a = aidx[m0 >> 11];
    const float s = scal[a];
    const int wr = wid >> 1, wc = wid & 1;      // wave: 16 rows x 32 xa-cols
    const int arow = (wr << 4) + (lane & 15);
    const int brow = (wc << 5) + (lane & 15);

    f32x4 acc[2];
    acc[0] = 0.f; acc[1] = 0.f;

    // zero Ps rows 16..63 once (3072 elems, 12/thread)
    {
        s16x4 z; z[0]=0; z[1]=0; z[2]=0; z[3]=0;
        #pragma unroll
        for (int j = 0; j < 3; ++j)
            *(s16x4*)(Ps + 1024 + tid * 12 + j * 4) = z;
    }

    // x coords: 2 rounds; round j: row = j*16 + (tid>>4), fp32 col = (tid&15)*4
    const int xrow_l = tid >> 4;
    const int xcol   = (tid & 15) << 2;
    const int wslot  = (tid & 15) >> 1;
    const int wsub   = (tid & 1) << 2;
    // P-tile coords: rows 0..15 from raw A (L2-resident), same swizzle convention
    const int prow  = tid >> 4;
    const int pcolg = tid & 15;
    const float* Arow = A + ((size_t)((a << 4) + prow) << 11) + (pcolg << 2);
    u16* pdst = Ps + (prow << 6) + ((((pcolg >> 1) ^ (prow & 7))) << 3) + ((pcolg & 1) << 2);

    for (int kt = 0; kt < NTM; ++kt) {
        const int k0 = kt << 6;
        float4 xv[2];
        #pragma unroll
        for (int j = 0; j < 2; ++j)
            xv[j] = *(const float4*)(x + ((size_t)(m0 + (j << 4) + xrow_l) << 11) + k0 + xcol);
        float4 av = *(const float4*)(Arow + k0);
        #pragma unroll
        for (int j = 0; j < 2; ++j) {
            const int row = (j << 4) + xrow_l;
            s16x4 c4;
            c4[0]=f2bf(xv[j].x); c4[1]=f2bf(xv[j].y); c4[2]=f2bf(xv[j].z); c4[3]=f2bf(xv[j].w);
            *(s16x4*)(Xs + (row << 6) + ((wslot ^ (row & 7)) << 3) + wsub) = c4;
            *(s16x4*)(xb + ((size_t)(m0 + row) << 11) + k0 + xcol) = c4;
        }
        {
            s16x4 a4;
            a4[0]=f2bf(av.x); a4[1]=f2bf(av.y); a4[2]=f2bf(av.z); a4[3]=f2bf(av.w);
            *(s16x4*)pdst = a4;
        }
        __syncthreads();
        #pragma unroll
        for (int kk = 0; kk < 2; ++kk) {
            const int sl = ((kk << 2) + (lane >> 4)) ^ (lane & 7);
            short8 af = *(const short8*)(Xs + (arow << 6) + (sl << 3));
            #pragma unroll
            for (int ni = 0; ni < 2; ++ni) {
                short8 bv = *(const short8*)(Ps + ((brow + ni * 16) << 6) + (sl << 3));
                acc[ni] = __builtin_amdgcn_mfma_f32_16x16x32_bf16(af, bv, acc[ni], 0, 0, 0);
            }
        }
        __syncthreads();
    }

    // epilogue -> xa row-major (m, 64)
    #pragma unroll
    for (int ni = 0; ni < 2; ++ni) {
        const int cc = (wc << 5) + ni * 16 + (lane & 15);
        #pragma unroll
        for (int rr = 0; rr < 4; ++rr) {
            const int mm = m0 + (wr << 4) + ((lane >> 4) << 2) + rr;
            xa[((size_t)mm << 6) + cc] = f2bf(acc[ni][rr] * s);
        }
    }
}

// ---------- main GEMM: r9 layout/swizzle/ledger, LATENCY-MATCHED prefetch:
// B(t+1) shallow -> buf c^1 (L2-hot, ~200cyc); A(t+2) deep -> buf c (HBM, ~900cyc).
// Read cadence 12/8/4/0 so ALL A-reads of buf c retire by P2 (race-free deep A stage). ----------
__global__ __launch_bounds__(512, 2) void k_gemm(
    const u16* __restrict__ xb, const u16* __restrict__ Wb,
    const u16* __restrict__ xa, const u16* __restrict__ Bp,
    const int* __restrict__ aidx, float* __restrict__ out)
{
    __shared__ __align__(16) u16 LDS[2 * 32768];   // [buf][A 256x64 | B 256x64] = 128 KB
    const int tid = threadIdx.x, lane = tid & 63, wid = tid >> 6;

    const int newbid = (blockIdx.x & 7) * 128 + (blockIdx.x >> 3);
    const int bm = newbid >> 3, bn = newbid & 7;
    const int m0 = bm << 8, n0 = bn << 8;
    const int wr = wid >> 2, wc = wid & 3;
    const int a = aidx[m0 >> 11];

    f32x4 acc[8][4];
    #pragma unroll
    for (int i = 0; i < 8; ++i)
        #pragma unroll
        for (int j = 0; j < 4; ++j) acc[i][j] = 0.0f;

    const int sc = ((tid & 7) ^ ((tid >> 3) & 7)) << 3;
    const int srw = tid >> 3;

    const int sl0 = (((lane >> 4)    ) ^ (lane & 7)) << 3;
    const int sl1 = (((lane >> 4) + 4) ^ (lane & 7)) << 3;
    const int aRowBase = (wr << 7) + (lane & 15);
    const int bRowBase = (wc << 6) + (lane & 15);

    short8 af0[4][2], af1[4][2], bv0[4], bv1[4];

    auto STG = [&](const u16* ptr, int stride, int rowbase, int kofs, int ldsofs) {
        const u16* s_ = ptr + ((size_t)(rowbase + srw)) * stride + kofs + sc;
        gload16(s_,                          &LDS[ldsofs + (tid << 3)]);
        gload16(s_ + ((size_t)stride << 6),  &LDS[ldsofs + 4096 + (tid << 3)]);
    };
    auto SA = [&](int tt, int h) {
        const int lo = ((tt & 1) << 15) + (h << 13);
        if (tt < NTM) STG(xb, 2048, m0 + (h << 7), tt << 6, lo);
        else          STG(xa, 64,   m0 + (h << 7), 0,       lo);
    };
    auto SB = [&](int tt, int h) {
        const int lo = ((tt & 1) << 15) + 16384 + (h << 13);
        if (tt < NTM) STG(Wb, 2048, n0 + (h << 7), tt << 6, lo);
        else          STG(Bp, 64,   (a << 11) + n0 + (h << 7), 0, lo);
    };

    #define BAR  __builtin_amdgcn_s_barrier()
    #define LGK0 do { asm volatile("s_waitcnt lgkmcnt(0)" ::: "memory"); \
                      __builtin_amdgcn_sched_barrier(0); } while (0)

    // A reads: both kk slots for one m-quadrant (8 ds_read_b128)
    #define RDA(dst, c_, mq_) do { _Pragma("unroll")                                \
        for (int mi = 0; mi < 4; ++mi) {                                            \
            const int row = aRowBase + ((mq_) << 6) + (mi << 4);                    \
            dst[mi][0] = *(const short8*)&LDS[((c_) << 15) + (row << 6) + sl0];     \
            dst[mi][1] = *(const short8*)&LDS[((c_) << 15) + (row << 6) + sl1];     \
        } } while (0)

    // B reads: one kk slot for all 4 n-frags (4 ds_read_b128)
    #define RDB(dst, c_, slx) do { _Pragma("unroll")                                \
        for (int ni = 0; ni < 4; ++ni) {                                            \
            const int row = bRowBase + (ni << 4);                                   \
            dst[ni] = *(const short8*)&LDS[((c_) << 15) + 16384 + (row << 6) + (slx)]; \
        } } while (0)

    #define MM(afA, bvA, kkI, mq_) do { __builtin_amdgcn_s_setprio(1); _Pragma("unroll") \
        for (int mi = 0; mi < 4; ++mi) _Pragma("unroll")                            \
        for (int ni = 0; ni < 4; ++ni)                                              \
            acc[(mq_) * 4 + mi][ni] = __builtin_amdgcn_mfma_f32_16x16x32_bf16(      \
                afA[mi][kkI], bvA[ni], acc[(mq_) * 4 + mi][ni], 0, 0, 0);           \
        __builtin_amdgcn_s_setprio(0); } while (0)

    // prologue: tile0 (A0,B0) + A1 deep; retire tile0, keep A1 (4 loads) in flight
    SA(0, 0); SA(0, 1); SB(0, 0); SB(0, 1); SA(1, 0); SA(1, 1);
    asm volatile("s_waitcnt vmcnt(4)" ::: "memory");
    BAR;

    for (int t = 0; t <= NTM; ++t) {
        const int c = t & 1;
        // P1: A mq0 (both kk) + B kk0 [12 reads]; stage B(t+1)h0 -> c^1
        RDA(af0, c, 0); RDB(bv0, c, sl0);
        if (t + 1 <= NTM) SB(t + 1, 0);
        BAR; LGK0; MM(af0, bv0, 0, 0); BAR;
        // P2: A mq1 (both kk) [8 reads]; stage B(t+1)h1 -> c^1
        RDA(af1, c, 1);
        if (t + 1 <= NTM) SB(t + 1, 1);
        BAR; LGK0; MM(af1, bv0, 0, 1); BAR;
        // P3: B kk1 [4 reads]; stage A(t+2)h0 -> buf c (A reads retired by P2) [deep]
        RDB(bv1, c, sl1);
        if (t + 2 <= NTM) SA(t + 2, 0);
        BAR; LGK0; MM(af0, bv1, 1, 0); BAR;
        // P4: stage A(t+2)h1 -> buf c [deep]; MFMA; counted retire
        if (t + 2 <= NTM) SA(t + 2, 1);
        BAR; MM(af1, bv1, 1, 1);
        if (t < NTM - 1)       asm volatile("s_waitcnt vmcnt(4)" ::: "memory");
        else if (t == NTM - 1) asm volatile("s_waitcnt vmcnt(0)" ::: "memory");
        BAR;
    }

    #undef MM
    #undef RDB
    #undef RDA
    #undef LGK0
    #undef BAR

    #pragma unroll
    for (int mi = 0; mi < 8; ++mi) {
        #pragma unroll
        for (int ni = 0; ni < 4; ++ni) {
            const int nn = n0 + (wc << 6) + ni * 16 + (lane & 15);
            #pragma unroll
            for (int r = 0; r < 4; ++r) {
                const int mm = m0 + (wr << 7) + mi * 16 + ((lane >> 4) << 2) + r;
                out[((size_t)mm << 11) + nn] = acc[mi][ni][r];
            }
        }
    }
}

extern "C" void kernel_launch(void* const* d_in, const int* in_sizes, int n_in,
                              void* d_out, int out_size, void* d_ws, size_t ws_size,
                              hipStream_t stream) {
    const float* x  = (const float*)d_in[0];
    const float* W  = (const float*)d_in[1];
    const float* A  = (const float*)d_in[2];
    const float* Bm = (const float*)d_in[3];
    const float* sc = (const float*)d_in[4];
    const int* aidx = (const int*)d_in[5];
    float* out = (float*)d_out;

    // ws layout (bytes): xb 128MiB | Wb 8MiB | (unused 2MiB) | Bp 2MiB | xa 4MiB
    char* ws = (char*)d_ws;
    u16* xb = (u16*)(ws);
    u16* Wb = (u16*)(ws + 134217728);
    u16* Bp = (u16*)(ws + 134217728 + 8388608 + 2097152);
    u16* xa = (u16*)(ws + 134217728 + 8388608 + 2097152 + 2097152);

    hipLaunchKernelGGL(k_pre,  dim3(7168), dim3(256), 0, stream,
                       x, W, A, Bm, sc, aidx, xb, Wb, Bp, xa);
    hipLaunchKernelGGL(k_gemm, dim3(1024), dim3(512), 0, stream,
                       xb, Wb, xa, Bp, aidx, out);
}

// Round 19
// 370.122 us; speedup vs baseline: 1.0160x; 1.0160x over previous
//
#include <hip/hip_runtime.h>
#include <stdint.h>

typedef unsigned short u16;
typedef __attribute__((ext_vector_type(4))) short s16x4;
typedef __attribute__((ext_vector_type(8))) short short8;
typedef __attribute__((ext_vector_type(4))) float f32x4;

// ---------- bf16 helpers (RNE) ----------
static __device__ __forceinline__ u16 f2bf(float f) {
    union { float f; uint32_t u; } c; c.f = f;
    uint32_t u = c.u;
    u += 0x7FFFu + ((u >> 16) & 1u);
    return (u16)(u >> 16);
}

// ---------- problem constants ----------
#define D_IN   2048
#define D_OUT  2048
#define MTOT   32768   // B*T
#define BK     64
#define NTM    32      // main K-tiles; tile 32 = LoRA tail

// async global->LDS, 16B/lane; LDS dest = wavebase + lane*16 (linear)
__device__ __forceinline__ void gload16(const u16* g, u16* l) {
    __builtin_amdgcn_global_load_lds(
        (const __attribute__((address_space(1))) void*)g,
        (__attribute__((address_space(3))) void*)l, 16, 0, 0);
}

// ---------- MERGED pre-pass: [0,1024) cast x + xa ; [1024,3072) W cast ; [3072,7168) Bp ----------
__global__ __launch_bounds__(256) void k_pre(
    const float* __restrict__ x, const float* __restrict__ W,
    const float* __restrict__ A, const float* __restrict__ Bm,
    const float* __restrict__ scal, const int* __restrict__ aidx,
    u16* __restrict__ xb, u16* __restrict__ Wb, u16* __restrict__ Bp,
    u16* __restrict__ xa)
{
    __shared__ __align__(16) u16 Xs[32 * BK];   // 4 KB
    __shared__ __align__(16) u16 Ps[64 * BK];   // 8 KB
    const int b = blockIdx.x, tid = threadIdx.x;

    if (b >= 1024) {
        if (b < 3072) {                   // W cast: 4M elems, 8/thread
            int i = ((b - 1024) * 256 + tid) * 8;
            const float4* p = (const float4*)(W + i);
            float4 v0 = p[0], v1 = p[1];
            short8 o;
            o[0]=f2bf(v0.x); o[1]=f2bf(v0.y); o[2]=f2bf(v0.z); o[3]=f2bf(v0.w);
            o[4]=f2bf(v1.x); o[5]=f2bf(v1.y); o[6]=f2bf(v1.z); o[7]=f2bf(v1.w);
            *(short8*)(Wb + i) = o;
        } else {                          // Bpad (a,n,64), cols 16..63 zero
            int i = (b - 3072) * 256 + tid;   // over 1048576
            int j = i & 63, n = (i >> 6) & 2047, a = i >> 17;
            Bp[i] = (j < 16) ? f2bf(Bm[((((a << 11) + n)) << 4) + j]) : (u16)0;
        }
        return;
    }

    // ---- cast + xa block: 32 rows of x ----
    const int lane = tid & 63, wid = tid >> 6;
    const int m0 = b << 5;
    const int a = aidx[m0 >> 11];
    const float s = scal[a];
    const int wr = wid >> 1, wc = wid & 1;      // wave: 16 rows x 32 xa-cols
    const int arow = (wr << 4) + (lane & 15);
    const int brow = (wc << 5) + (lane & 15);

    f32x4 acc[2];
    acc[0] = 0.f; acc[1] = 0.f;

    // zero Ps rows 16..63 once (3072 elems, 12/thread)
    {
        s16x4 z; z[0]=0; z[1]=0; z[2]=0; z[3]=0;
        #pragma unroll
        for (int j = 0; j < 3; ++j)
            *(s16x4*)(Ps + 1024 + tid * 12 + j * 4) = z;
    }

    // x coords: 2 rounds; round j: row = j*16 + (tid>>4), fp32 col = (tid&15)*4
    const int xrow_l = tid >> 4;
    const int xcol   = (tid & 15) << 2;
    const int wslot  = (tid & 15) >> 1;
    const int wsub   = (tid & 1) << 2;
    // P-tile coords: rows 0..15 from raw A (L2-resident), same swizzle convention
    const int prow  = tid >> 4;
    const int pcolg = tid & 15;
    const float* Arow = A + ((size_t)((a << 4) + prow) << 11) + (pcolg << 2);
    u16* pdst = Ps + (prow << 6) + ((((pcolg >> 1) ^ (prow & 7))) << 3) + ((pcolg & 1) << 2);

    for (int kt = 0; kt < NTM; ++kt) {
        const int k0 = kt << 6;
        float4 xv[2];
        #pragma unroll
        for (int j = 0; j < 2; ++j)
            xv[j] = *(const float4*)(x + ((size_t)(m0 + (j << 4) + xrow_l) << 11) + k0 + xcol);
        float4 av = *(const float4*)(Arow + k0);
        #pragma unroll
        for (int j = 0; j < 2; ++j) {
            const int row = (j << 4) + xrow_l;
            s16x4 c4;
            c4[0]=f2bf(xv[j].x); c4[1]=f2bf(xv[j].y); c4[2]=f2bf(xv[j].z); c4[3]=f2bf(xv[j].w);
            *(s16x4*)(Xs + (row << 6) + ((wslot ^ (row & 7)) << 3) + wsub) = c4;
            *(s16x4*)(xb + ((size_t)(m0 + row) << 11) + k0 + xcol) = c4;
        }
        {
            s16x4 a4;
            a4[0]=f2bf(av.x); a4[1]=f2bf(av.y); a4[2]=f2bf(av.z); a4[3]=f2bf(av.w);
            *(s16x4*)pdst = a4;
        }
        __syncthreads();
        #pragma unroll
        for (int kk = 0; kk < 2; ++kk) {
            const int sl = ((kk << 2) + (lane >> 4)) ^ (lane & 7);
            short8 af = *(const short8*)(Xs + (arow << 6) + (sl << 3));
            #pragma unroll
            for (int ni = 0; ni < 2; ++ni) {
                short8 bv = *(const short8*)(Ps + ((brow + ni * 16) << 6) + (sl << 3));
                acc[ni] = __builtin_amdgcn_mfma_f32_16x16x32_bf16(af, bv, acc[ni], 0, 0, 0);
            }
        }
        __syncthreads();
    }

    // epilogue -> xa row-major (m, 64)
    #pragma unroll
    for (int ni = 0; ni < 2; ++ni) {
        const int cc = (wc << 5) + ni * 16 + (lane & 15);
        #pragma unroll
        for (int rr = 0; rr < 4; ++rr) {
            const int mm = m0 + (wr << 4) + ((lane >> 4) << 2) + rr;
            xa[((size_t)mm << 6) + cc] = f2bf(acc[ni][rr] * s);
        }
    }
}

// ---------- main GEMM (best measured, r9/r16): 256x256, BK=64, 8 waves,
// 4-phase/K-tile, half-tile staging (1/phase), counted vmcnt(4), proven swizzle ----------
__global__ __launch_bounds__(512, 2) void k_gemm(
    const u16* __restrict__ xb, const u16* __restrict__ Wb,
    const u16* __restrict__ xa, const u16* __restrict__ Bp,
    const int* __restrict__ aidx, float* __restrict__ out)
{
    __shared__ __align__(16) u16 LDS[2 * 32768];   // [buf][A 256x64 | B 256x64] = 128 KB
    const int tid = threadIdx.x, lane = tid & 63, wid = tid >> 6;

    const int newbid = (blockIdx.x & 7) * 128 + (blockIdx.x >> 3);
    const int bm = newbid >> 3, bn = newbid & 7;
    const int m0 = bm << 8, n0 = bn << 8;
    const int wr = wid >> 2, wc = wid & 3;
    const int a = aidx[m0 >> 11];

    f32x4 acc[8][4];
    #pragma unroll
    for (int i = 0; i < 8; ++i)
        #pragma unroll
        for (int j = 0; j < 4; ++j) acc[i][j] = 0.0f;

    const int sc = ((tid & 7) ^ ((tid >> 3) & 7)) << 3;
    const int srw = tid >> 3;

    const int sl0 = (((lane >> 4)    ) ^ (lane & 7)) << 3;
    const int sl1 = (((lane >> 4) + 4) ^ (lane & 7)) << 3;
    const int aRowBase = (wr << 7) + (lane & 15);
    const int bRowBase = (wc << 6) + (lane & 15);

    short8 af[4][2], bv[4][2];

    auto STG = [&](const u16* ptr, int stride, int rowbase, int kofs, int ldsofs) {
        const u16* s_ = ptr + ((size_t)(rowbase + srw)) * stride + kofs + sc;
        gload16(s_,                          &LDS[ldsofs + (tid << 3)]);
        gload16(s_ + ((size_t)stride << 6),  &LDS[ldsofs + 4096 + (tid << 3)]);
    };
    auto SA = [&](int tt, int h) {
        const int lo = ((tt & 1) << 15) + (h << 13);
        if (tt < NTM) STG(xb, 2048, m0 + (h << 7), tt << 6, lo);
        else          STG(xa, 64,   m0 + (h << 7), 0,       lo);
    };
    auto SB = [&](int tt, int h) {
        const int lo = ((tt & 1) << 15) + 16384 + (h << 13);
        if (tt < NTM) STG(Wb, 2048, n0 + (h << 7), tt << 6, lo);
        else          STG(Bp, 64,   (a << 11) + n0 + (h << 7), 0, lo);
    };

    #define BAR  __builtin_amdgcn_s_barrier()
    #define LGK0 do { asm volatile("s_waitcnt lgkmcnt(0)" ::: "memory"); \
                      __builtin_amdgcn_sched_barrier(0); } while (0)

    #define RDA(c_, mq_) do { _Pragma("unroll")                                     \
        for (int mi = 0; mi < 4; ++mi) {                                            \
            const int row = aRowBase + ((mq_) << 6) + (mi << 4);                    \
            af[mi][0] = *(const short8*)&LDS[((c_) << 15) + (row << 6) + sl0];      \
            af[mi][1] = *(const short8*)&LDS[((c_) << 15) + (row << 6) + sl1];      \
        } } while (0)

    #define RDB(c_, ni_) do {                                                       \
            const int row = bRowBase + ((ni_) << 4);                                \
            bv[ni_][0] = *(const short8*)&LDS[((c_) << 15) + 16384 + (row << 6) + sl0]; \
            bv[ni_][1] = *(const short8*)&LDS[((c_) << 15) + 16384 + (row << 6) + sl1]; \
        } while (0)

    #define MM(mq_, ns_) do { __builtin_amdgcn_s_setprio(1); _Pragma("unroll")      \
        for (int kk = 0; kk < 2; ++kk) _Pragma("unroll")                            \
        for (int mi = 0; mi < 4; ++mi) _Pragma("unroll")                            \
        for (int j = 0; j < 2; ++j)                                                 \
            acc[(mq_) * 4 + mi][(ns_) * 2 + j] =                                    \
                __builtin_amdgcn_mfma_f32_16x16x32_bf16(af[mi][kk],                 \
                    bv[(ns_) * 2 + j][kk], acc[(mq_) * 4 + mi][(ns_) * 2 + j], 0, 0, 0); \
        __builtin_amdgcn_s_setprio(0); } while (0)

    SA(0, 0); SA(0, 1); SB(0, 0); SB(0, 1); SB(1, 0); SB(1, 1);
    asm volatile("s_waitcnt vmcnt(4)" ::: "memory");
    BAR;

    for (int t = 0; t <= NTM; ++t) {
        const int c = t & 1;
        RDB(c, 0); RDB(c, 1); RDA(c, 0);
        if (t + 1 <= NTM) SA(t + 1, 0);
        BAR; LGK0; MM(0, 0); BAR;
        RDB(c, 2); RDB(c, 3);
        if (t + 1 <= NTM) SA(t + 1, 1);
        BAR; LGK0; MM(0, 1); BAR;
        RDA(c, 1);
        if (t + 2 <= NTM) SB(t + 2, 0);
        BAR; LGK0; MM(1, 0); BAR;
        if (t + 2 <= NTM) SB(t + 2, 1);
        BAR; MM(1, 1);
        if (t < NTM - 1)      asm volatile("s_waitcnt vmcnt(4)" ::: "memory");
        else if (t == NTM - 1) asm volatile("s_waitcnt vmcnt(0)" ::: "memory");
        BAR;
    }

    #undef MM
    #undef RDB
    #undef RDA
    #undef LGK0
    #undef BAR

    #pragma unroll
    for (int mi = 0; mi < 8; ++mi) {
        #pragma unroll
        for (int ni = 0; ni < 4; ++ni) {
            const int nn = n0 + (wc << 6) + ni * 16 + (lane & 15);
            #pragma unroll
            for (int r = 0; r < 4; ++r) {
                const int mm = m0 + (wr << 7) + mi * 16 + ((lane >> 4) << 2) + r;
                out[((size_t)mm << 11) + nn] = acc[mi][ni][r];
            }
        }
    }
}

extern "C" void kernel_launch(void* const* d_in, const int* in_sizes, int n_in,
                              void* d_out, int out_size, void* d_ws, size_t ws_size,
                              hipStream_t stream) {
    const float* x  = (const float*)d_in[0];
    const float* W  = (const float*)d_in[1];
    const float* A  = (const float*)d_in[2];
    const float* Bm = (const float*)d_in[3];
    const float* sc = (const float*)d_in[4];
    const int* aidx = (const int*)d_in[5];
    float* out = (float*)d_out;

    // ws layout (bytes): xb 128MiB | Wb 8MiB | (unused 2MiB) | Bp 2MiB | xa 4MiB
    char* ws = (char*)d_ws;
    u16* xb = (u16*)(ws);
    u16* Wb = (u16*)(ws + 134217728);
    u16* Bp = (u16*)(ws + 134217728 + 8388608 + 2097152);
    u16* xa = (u16*)(ws + 134217728 + 8388608 + 2097152 + 2097152);

    hipLaunchKernelGGL(k_pre,  dim3(7168), dim3(256), 0, stream,
                       x, W, A, Bm, sc, aidx, xb, Wb, Bp, xa);
    hipLaunchKernelGGL(k_gemm, dim3(1024), dim3(512), 0, stream,
                       xb, Wb, xa, Bp, aidx, out);
}